// Round 5
// baseline (288.336 us; speedup 1.0000x reference)
//
#include <hip/hip_runtime.h>
#include <math.h>

// Problem constants
#define BB 2
#define SS 2048
#define DD 256
#define NTOK (BB * SS)          // 4096
#define N_QK 8192
#define N_V  8192
#define NCPS 32
#define MPC  16
#define NC   144                // 9 * MPC candidates per side
#define K_QK 32
#define K_V  64
#define OUT_GATES (3 * NTOK * NC)   // offset of pos_loss scalar
#define WS_COUNTER_OFF (4 * NTOK)   // float index of the atomic counter in ws

__global__ __launch_bounds__(256) void router_main(
    const float* __restrict__ x,
    const float* __restrict__ qk_neurons,
    const float* __restrict__ v_neurons,
    const float* __restrict__ neuron_pos,
    const float* __restrict__ W_pos_qk, const float* __restrict__ b_pos_qk,
    const float* __restrict__ W_pos_v,  const float* __restrict__ b_pos_v,
    const float* __restrict__ W_tau,    const float* __restrict__ b_tau,
    const int* __restrict__ cm_qk, const int* __restrict__ cm_v,
    float* __restrict__ out, float* __restrict__ ws)
{
    const int token = blockIdx.x;          // b*S + s
    const int tid   = threadIdx.x;
    const int lane  = tid & 63, wid = tid >> 6;

    __shared__ __align__(16) float  x_s[DD];
    __shared__ float  scal[8];             // [0..1] qk_pos, [2..3] v_pos, [4..6] tau
    __shared__ double partd[4][7];
    __shared__ int    ci_s[2][NC];         // raw cell_map entries (may be -1)
    __shared__ __align__(16) float sc_s[2][NC];  // scores (with -1e9 fill)
    __shared__ float  d_s[2][NC];          // squared pos distance
    __shared__ __align__(16) float eg3[3][NC];   // exp_gate per gate
    __shared__ float  tc2[2][NC];          // rank-threshold candidates (scores)
    __shared__ int    flag_s;
    __shared__ double redd[4][4];

    // ---- Phase A: load x row, compute 7 small dots in double ----
    float xv = x[(size_t)token * DD + tid];
    x_s[tid] = xv;
    float2 wqk = ((const float2*)W_pos_qk)[tid];
    float2 wv2 = ((const float2*)W_pos_v)[tid];
    double p[7];
    p[0] = (double)xv * (double)wqk.x;
    p[1] = (double)xv * (double)wqk.y;
    p[2] = (double)xv * (double)wv2.x;
    p[3] = (double)xv * (double)wv2.y;
    p[4] = (double)xv * (double)W_tau[tid * 3 + 0];
    p[5] = (double)xv * (double)W_tau[tid * 3 + 1];
    p[6] = (double)xv * (double)W_tau[tid * 3 + 2];
    #pragma unroll
    for (int j = 0; j < 7; ++j) {
        double v = p[j];
        for (int o = 32; o; o >>= 1) v += __shfl_down(v, o, 64);
        p[j] = v;
    }
    if (lane == 0) {
        #pragma unroll
        for (int j = 0; j < 7; ++j) partd[wid][j] = p[j];
    }
    __syncthreads();
    if (tid < 7) {
        double v = partd[0][tid] + partd[1][tid] + partd[2][tid] + partd[3][tid];
        float bias = (tid < 2) ? b_pos_qk[tid]
                   : (tid < 4) ? b_pos_v[tid - 2]
                               : b_tau[tid - 4];
        scal[tid] = (float)v + bias;       // f32 dot result + f32 bias (matches ref order)
    }
    __syncthreads();

    // ---- Phase B: candidate lookup + position distances ----
    for (int c = tid; c < 2 * NC; c += 256) {
        int side = (c >= NC);
        int n    = side ? c - NC : c;
        float px = scal[side * 2 + 0], py = scal[side * 2 + 1];
        int cx = (int)(((px + 4.0f) / 8.0f) * 32.0f);
        int cy = (int)(((py + 4.0f) / 8.0f) * 32.0f);
        cx = min(max(cx, 0), NCPS - 1);
        cy = min(max(cy, 0), NCPS - 1);
        int o = n / MPC, slot = n % MPC;
        int nx = min(max(cx + (o / 3 - 1), 0), NCPS - 1);
        int ny = min(max(cy + (o % 3 - 1), 0), NCPS - 1);
        int idx = nx * NCPS + ny;
        int cand = (side ? cm_v : cm_qk)[idx * MPC + slot];
        ci_s[side][n] = cand;
        const float* npos = neuron_pos + (side ? (size_t)N_QK * 2 : 0);
        int cidx = max(cand, 0);
        float dx = px - npos[cidx * 2 + 0];
        float dy = py - npos[cidx * 2 + 1];
        d_s[side][n] = dx * dx + dy * dy;
    }
    __syncthreads();

    // ---- Phase C: 288 dots; 16 lanes/row, 4 rows/wave-instr (coalesced 256B segs) ----
    {
        const int sub = lane >> 4;         // 0..3: which row of the group
        const int c   = lane & 15;         // 0..15: position within row
        const int rowbase = wid * 72;      // waves 0,1 -> side 0 ; waves 2,3 -> side 1
        const float4* x4 = (const float4*)x_s;
        #pragma unroll 2
        for (int g = 0; g < 18; ++g) {
            int r    = rowbase + g * 4 + sub;
            int side = (r >= NC);
            int n    = r - side * NC;
            int cand = ci_s[side][n];
            const float4* row = (const float4*)((side ? v_neurons : qk_neurons)
                                                + (size_t)max(cand, 0) * DD);
            double ax = 0.0, ay = 0.0, az = 0.0, aw = 0.0;
            #pragma unroll
            for (int k = 0; k < 4; ++k) {
                float4 rr = row[c + 16 * k];
                float4 xx = x4[c + 16 * k];
                ax = fma((double)rr.x, (double)xx.x, ax);
                ay = fma((double)rr.y, (double)xx.y, ay);
                az = fma((double)rr.z, (double)xx.z, az);
                aw = fma((double)rr.w, (double)xx.w, aw);
            }
            double acc = (ax + ay) + (az + aw);
            acc += __shfl_xor(acc, 1, 64);
            acc += __shfl_xor(acc, 2, 64);
            acc += __shfl_xor(acc, 4, 64);
            acc += __shfl_xor(acc, 8, 64);
            if (c == 0) sc_s[side][n] = (cand >= 0) ? (float)acc : -1e9f;
        }
    }
    __syncthreads();

    // ---- Phase D1: exp_gate for all 3 gates ----
    for (int idx = tid; idx < 3 * NC; idx += 256) {
        int g = (idx >= 2 * NC) ? 2 : (idx >= NC);
        int j = idx - g * NC;
        float s   = sc_s[g == 2][j];
        float raw = s - scal[4 + g];
        float gate = (raw > 0.0f) ? raw : 1e-8f * expf(raw);
        eg3[g][j] = expf(gate) - 1.0f;
    }
    // ---- Phase D2: rank candidates on SCORES (monotonic h => same k-th element) ----
    for (int idx = tid; idx < 2 * NC; idx += 256) {
        int side = (idx >= NC);
        int n    = idx - side * NC;
        float my = sc_s[side][n];
        const float4* s4 = (const float4*)&sc_s[side][0];
        int cnt = 0;
        #pragma unroll
        for (int q = 0; q < NC / 4; ++q) {
            float4 e = s4[q];
            cnt += (e.x > my) + (e.y > my) + (e.z > my) + (e.w > my);
        }
        int k = side ? K_V : K_QK;
        tc2[side][n] = (cnt < k) ? my : 3.402823466e38f;
    }
    __syncthreads();

    // ---- Phase D3: one wave per gate ----
    if (wid < 3) {
        const int g = wid, side = (g == 2);
        const bool has2 = (lane < 16);
        float t0 = tc2[side][lane], t1 = tc2[side][lane + 64];
        float t2 = has2 ? tc2[side][lane + 128] : 3.402823466e38f;
        float e0 = eg3[g][lane],   e1 = eg3[g][lane + 64];
        float e2 = has2 ? eg3[g][lane + 128] : 0.0f;
        float mn = fminf(fminf(t0, t1), t2);
        float mx = fmaxf(fmaxf(e0, e1), e2);
        #pragma unroll
        for (int o = 32; o; o >>= 1) {
            mn = fminf(mn, __shfl_xor(mn, o, 64));
            mx = fmaxf(mx, __shfl_xor(mx, o, 64));
        }
        // thr = h(s_k, tau_g): identical f32 ops as D1 => bit-identical to ref's k-th eg
        float rawk  = mn - scal[4 + g];
        float gatek = (rawk > 0.0f) ? rawk : 1e-8f * expf(rawk);
        float thr   = expf(gatek) - 1.0f;

        float k0 = (e0 >= thr) ? e0 : 0.0f;
        float k1 = (e1 >= thr) ? e1 : 0.0f;
        float k2 = (has2 && e2 >= thr) ? e2 : 0.0f;
        float sum = k0 + k1 + k2;
        #pragma unroll
        for (int o = 32; o; o >>= 1) sum += __shfl_xor(sum, o, 64);
        const float gs = sum + 1e-8f;
        const float strength = tanhf(mx);
        float o0 = k0 / gs * strength;
        float o1 = k1 / gs * strength;
        float o2 = k2 / gs * strength;
        float* og = out + ((size_t)g * NTOK + token) * NC;
        og[lane]      = o0;
        og[lane + 64] = o1;
        if (has2) og[lane + 128] = o2;

        if (g != 1) {
            float m0 = (ci_s[side][lane]       >= 0) ? 1.0f : 0.0f;
            float m1 = (ci_s[side][lane + 64]  >= 0) ? 1.0f : 0.0f;
            float m2 = (has2 && ci_s[side][lane + 128] >= 0) ? 1.0f : 0.0f;
            float w = o0 * d_s[side][lane] * m0 + o1 * d_s[side][lane + 64] * m1;
            if (has2) w += o2 * d_s[side][lane + 128] * m2;
            float c = m0 + m1 + m2;
            #pragma unroll
            for (int o = 32; o; o >>= 1) {
                w += __shfl_xor(w, o, 64);
                c += __shfl_xor(c, o, 64);
            }
            if (lane == 0) {
                ws[(size_t)token * 4 + (side ? 2 : 0)] = w;
                ws[(size_t)token * 4 + (side ? 3 : 1)] = c;
            }
        }
    }
    __syncthreads();

    // ---- Fused finalize: last block reduces the per-token partials ----
    if (tid == 0) {
        __threadfence();   // publish this block's ws stores device-wide
        unsigned old = atomicAdd((unsigned*)(ws + WS_COUNTER_OFF), 1u);
        flag_s = (old == NTOK - 1);
    }
    __syncthreads();
    if (flag_s) {
        __threadfence();   // acquire: see all blocks' ws stores
        double wq = 0, cq = 0, wv = 0, cv = 0;
        const float4* w4 = (const float4*)ws;     // [token] = {wq, cq, wv, cv}
        for (int i = tid; i < NTOK; i += 256) {
            float4 v = w4[i];
            wq += (double)v.x; cq += (double)v.y;
            wv += (double)v.z; cv += (double)v.w;
        }
        #pragma unroll
        for (int o = 32; o; o >>= 1) {
            wq += __shfl_down(wq, o, 64);
            cq += __shfl_down(cq, o, 64);
            wv += __shfl_down(wv, o, 64);
            cv += __shfl_down(cv, o, 64);
        }
        if (lane == 0) { redd[wid][0] = wq; redd[wid][1] = cq; redd[wid][2] = wv; redd[wid][3] = cv; }
        __syncthreads();
        if (tid == 0) {
            double a = 0, b = 0, c = 0, d = 0;
            #pragma unroll
            for (int i = 0; i < 4; ++i) {
                a += redd[i][0]; b += redd[i][1]; c += redd[i][2]; d += redd[i][3];
            }
            out[OUT_GATES] = (float)(a / (b + 1e-8) + c / (d + 1e-8));
        }
    }
}

extern "C" void kernel_launch(void* const* d_in, const int* in_sizes, int n_in,
                              void* d_out, int out_size, void* d_ws, size_t ws_size,
                              hipStream_t stream) {
    const float* x          = (const float*)d_in[0];
    const float* qk_neurons = (const float*)d_in[1];
    const float* v_neurons  = (const float*)d_in[2];
    const float* neuron_pos = (const float*)d_in[3];
    const float* W_pos_qk   = (const float*)d_in[4];
    const float* b_pos_qk   = (const float*)d_in[5];
    const float* W_pos_v    = (const float*)d_in[6];
    const float* b_pos_v    = (const float*)d_in[7];
    const float* W_tau      = (const float*)d_in[8];
    const float* b_tau      = (const float*)d_in[9];
    const int*   cm_qk      = (const int*)d_in[10];
    const int*   cm_v       = (const int*)d_in[11];

    float* out = (float*)d_out;
    float* ws  = (float*)d_ws;

    // zero the completion counter (graph-capture-safe async memset)
    hipMemsetAsync(ws + WS_COUNTER_OFF, 0, sizeof(unsigned), stream);

    router_main<<<NTOK, 256, 0, stream>>>(
        x, qk_neurons, v_neurons, neuron_pos,
        W_pos_qk, b_pos_qk, W_pos_v, b_pos_v, W_tau, b_tau,
        cm_qk, cm_v, out, ws);
}

// Round 8
// 194.300 us; speedup vs baseline: 1.4840x; 1.4840x over previous
//
#include <hip/hip_runtime.h>
#include <math.h>

// Problem constants
#define BB 2
#define SS 2048
#define DD 256
#define NTOK (BB * SS)          // 4096
#define N_QK 8192
#define N_V  8192
#define NCPS 32
#define MPC  16
#define NC   144                // 9 * MPC candidates per side
#define K_QK 32
#define K_V  64
#define OUT_GATES (3 * NTOK * NC)   // offset of pos_loss scalar

__global__ __launch_bounds__(256) void router_main(
    const float* __restrict__ x,
    const float* __restrict__ qk_neurons,
    const float* __restrict__ v_neurons,
    const float* __restrict__ neuron_pos,
    const float* __restrict__ W_pos_qk, const float* __restrict__ b_pos_qk,
    const float* __restrict__ W_pos_v,  const float* __restrict__ b_pos_v,
    const float* __restrict__ W_tau,    const float* __restrict__ b_tau,
    const int* __restrict__ cm_qk, const int* __restrict__ cm_v,
    float* __restrict__ out, float* __restrict__ ws)
{
    const int token = blockIdx.x;          // b*S + s
    const int tid   = threadIdx.x;
    const int lane  = tid & 63, wid = tid >> 6;

    __shared__ __align__(16) float  x_s[DD];
    __shared__ float  scal[8];             // [0..1] qk_pos, [2..3] v_pos, [4..6] tau
    __shared__ double partd[4][7];
    __shared__ int    ci_s[2][NC];         // raw cell_map entries (may be -1)
    __shared__ __align__(16) float sc_s[2][NC];  // scores (with -1e9 fill)
    __shared__ float  d_s[2][NC];          // squared pos distance
    __shared__ __align__(16) float eg3[3][NC];   // exp_gate per gate
    __shared__ float  tc2[2][NC];          // rank-threshold candidates (scores)

    // ---- Phase A: load x row, compute 7 small dots in double ----
    float xv = x[(size_t)token * DD + tid];
    x_s[tid] = xv;
    float2 wqk = ((const float2*)W_pos_qk)[tid];
    float2 wv2 = ((const float2*)W_pos_v)[tid];
    double p[7];
    p[0] = (double)xv * (double)wqk.x;
    p[1] = (double)xv * (double)wqk.y;
    p[2] = (double)xv * (double)wv2.x;
    p[3] = (double)xv * (double)wv2.y;
    p[4] = (double)xv * (double)W_tau[tid * 3 + 0];
    p[5] = (double)xv * (double)W_tau[tid * 3 + 1];
    p[6] = (double)xv * (double)W_tau[tid * 3 + 2];
    #pragma unroll
    for (int j = 0; j < 7; ++j) {
        double v = p[j];
        for (int o = 32; o; o >>= 1) v += __shfl_down(v, o, 64);
        p[j] = v;
    }
    if (lane == 0) {
        #pragma unroll
        for (int j = 0; j < 7; ++j) partd[wid][j] = p[j];
    }
    __syncthreads();
    if (tid < 7) {
        double v = partd[0][tid] + partd[1][tid] + partd[2][tid] + partd[3][tid];
        float bias = (tid < 2) ? b_pos_qk[tid]
                   : (tid < 4) ? b_pos_v[tid - 2]
                               : b_tau[tid - 4];
        scal[tid] = (float)v + bias;       // f32 dot result + f32 bias (matches ref order)
    }
    __syncthreads();

    // ---- Phase B: candidate lookup + position distances ----
    for (int c = tid; c < 2 * NC; c += 256) {
        int side = (c >= NC);
        int n    = side ? c - NC : c;
        float px = scal[side * 2 + 0], py = scal[side * 2 + 1];
        int cx = (int)(((px + 4.0f) / 8.0f) * 32.0f);
        int cy = (int)(((py + 4.0f) / 8.0f) * 32.0f);
        cx = min(max(cx, 0), NCPS - 1);
        cy = min(max(cy, 0), NCPS - 1);
        int o = n / MPC, slot = n % MPC;
        int nx = min(max(cx + (o / 3 - 1), 0), NCPS - 1);
        int ny = min(max(cy + (o % 3 - 1), 0), NCPS - 1);
        int idx = nx * NCPS + ny;
        int cand = (side ? cm_v : cm_qk)[idx * MPC + slot];
        ci_s[side][n] = cand;
        const float* npos = neuron_pos + (side ? (size_t)N_QK * 2 : 0);
        int cidx = max(cand, 0);
        float dx = px - npos[cidx * 2 + 0];
        float dy = py - npos[cidx * 2 + 1];
        d_s[side][n] = dx * dx + dy * dy;
    }
    __syncthreads();

    // ---- Phase C: 288 dots; quad-of-lanes per row, TWO rows per iteration (ILP) ----
    {
        const int quad = tid >> 2, ql = tid & 3;   // quad 0..63
        const float4* x4 = (const float4*)x_s;
        #pragma unroll
        for (int j = 0; j < 4; j += 2) {
            const int c0 = quad + 64 * j, c1 = quad + 64 * (j + 1);
            const int side0 = (c0 >= NC), n0 = c0 - side0 * NC;
            const int side1 = (c1 >= NC), n1 = c1 - side1 * NC;
            const int cand0 = ci_s[side0][n0];
            const int cand1 = ci_s[side1][n1];
            const float4* r0 = (const float4*)((side0 ? v_neurons : qk_neurons)
                                               + (size_t)max(cand0, 0) * DD);
            const float4* r1 = (const float4*)((side1 ? v_neurons : qk_neurons)
                                               + (size_t)max(cand1, 0) * DD);
            double a0x = 0, a0y = 0, a0z = 0, a0w = 0;
            double a1x = 0, a1y = 0, a1z = 0, a1w = 0;
            #pragma unroll
            for (int i = ql; i < 64; i += 4) {
                float4 ra = r0[i];
                float4 rb = r1[i];
                float4 xx = x4[i];
                a0x = fma((double)ra.x, (double)xx.x, a0x);
                a0y = fma((double)ra.y, (double)xx.y, a0y);
                a0z = fma((double)ra.z, (double)xx.z, a0z);
                a0w = fma((double)ra.w, (double)xx.w, a0w);
                a1x = fma((double)rb.x, (double)xx.x, a1x);
                a1y = fma((double)rb.y, (double)xx.y, a1y);
                a1z = fma((double)rb.z, (double)xx.z, a1z);
                a1w = fma((double)rb.w, (double)xx.w, a1w);
            }
            double acc0 = (a0x + a0y) + (a0z + a0w);
            double acc1 = (a1x + a1y) + (a1z + a1w);
            acc0 += __shfl_xor(acc0, 1, 64);
            acc0 += __shfl_xor(acc0, 2, 64);
            acc1 += __shfl_xor(acc1, 1, 64);
            acc1 += __shfl_xor(acc1, 2, 64);
            if (ql == 0) {
                sc_s[side0][n0] = (cand0 >= 0) ? (float)acc0 : -1e9f;
                sc_s[side1][n1] = (cand1 >= 0) ? (float)acc1 : -1e9f;
            }
        }
        // tail: rows 256..287 handled by quads 0..31
        if (quad < 32) {
            const int c0 = 256 + quad;             // always side 1
            const int n0 = c0 - NC;
            const int cand0 = ci_s[1][n0];
            const float4* r0 = (const float4*)(v_neurons + (size_t)max(cand0, 0) * DD);
            double ax = 0, ay = 0, az = 0, aw = 0;
            #pragma unroll
            for (int i = ql; i < 64; i += 4) {
                float4 ra = r0[i];
                float4 xx = x4[i];
                ax = fma((double)ra.x, (double)xx.x, ax);
                ay = fma((double)ra.y, (double)xx.y, ay);
                az = fma((double)ra.z, (double)xx.z, az);
                aw = fma((double)ra.w, (double)xx.w, aw);
            }
            double acc = (ax + ay) + (az + aw);
            acc += __shfl_xor(acc, 1, 64);
            acc += __shfl_xor(acc, 2, 64);
            if (ql == 0) sc_s[1][n0] = (cand0 >= 0) ? (float)acc : -1e9f;
        }
    }
    __syncthreads();

    // ---- Phase D1: exp_gate for all 3 gates ----
    for (int idx = tid; idx < 3 * NC; idx += 256) {
        int g = (idx >= 2 * NC) ? 2 : (idx >= NC);
        int j = idx - g * NC;
        float s   = sc_s[g == 2][j];
        float raw = s - scal[4 + g];
        float gate = (raw > 0.0f) ? raw : 1e-8f * expf(raw);
        eg3[g][j] = expf(gate) - 1.0f;
    }
    // ---- Phase D2: rank candidates on SCORES (monotonic h => same k-th element) ----
    for (int idx = tid; idx < 2 * NC; idx += 256) {
        int side = (idx >= NC);
        int n    = idx - side * NC;
        float my = sc_s[side][n];
        const float4* s4 = (const float4*)&sc_s[side][0];
        int cnt = 0;
        #pragma unroll
        for (int q = 0; q < NC / 4; ++q) {
            float4 e = s4[q];
            cnt += (e.x > my) + (e.y > my) + (e.z > my) + (e.w > my);
        }
        int k = side ? K_V : K_QK;
        tc2[side][n] = (cnt < k) ? my : 3.402823466e38f;
    }
    __syncthreads();

    // ---- Phase D3: one wave per gate ----
    if (wid < 3) {
        const int g = wid, side = (g == 2);
        const bool has2 = (lane < 16);
        float t0 = tc2[side][lane], t1 = tc2[side][lane + 64];
        float t2 = has2 ? tc2[side][lane + 128] : 3.402823466e38f;
        float e0 = eg3[g][lane],   e1 = eg3[g][lane + 64];
        float e2 = has2 ? eg3[g][lane + 128] : 0.0f;
        float mn = fminf(fminf(t0, t1), t2);
        float mx = fmaxf(fmaxf(e0, e1), e2);
        #pragma unroll
        for (int o = 32; o; o >>= 1) {
            mn = fminf(mn, __shfl_xor(mn, o, 64));
            mx = fmaxf(mx, __shfl_xor(mx, o, 64));
        }
        // thr = h(s_k, tau_g): identical f32 ops as D1 => bit-identical to ref's k-th eg
        float rawk  = mn - scal[4 + g];
        float gatek = (rawk > 0.0f) ? rawk : 1e-8f * expf(rawk);
        float thr   = expf(gatek) - 1.0f;

        float k0 = (e0 >= thr) ? e0 : 0.0f;
        float k1 = (e1 >= thr) ? e1 : 0.0f;
        float k2 = (has2 && e2 >= thr) ? e2 : 0.0f;
        float sum = k0 + k1 + k2;
        #pragma unroll
        for (int o = 32; o; o >>= 1) sum += __shfl_xor(sum, o, 64);
        const float gs = sum + 1e-8f;
        const float strength = tanhf(mx);
        float o0 = k0 / gs * strength;
        float o1 = k1 / gs * strength;
        float o2 = k2 / gs * strength;
        float* og = out + ((size_t)g * NTOK + token) * NC;
        og[lane]      = o0;
        og[lane + 64] = o1;
        if (has2) og[lane + 128] = o2;

        if (g != 1) {
            float m0 = (ci_s[side][lane]       >= 0) ? 1.0f : 0.0f;
            float m1 = (ci_s[side][lane + 64]  >= 0) ? 1.0f : 0.0f;
            float m2 = (has2 && ci_s[side][lane + 128] >= 0) ? 1.0f : 0.0f;
            float w = o0 * d_s[side][lane] * m0 + o1 * d_s[side][lane + 64] * m1;
            if (has2) w += o2 * d_s[side][lane + 128] * m2;
            float c = m0 + m1 + m2;
            #pragma unroll
            for (int o = 32; o; o >>= 1) {
                w += __shfl_xor(w, o, 64);
                c += __shfl_xor(c, o, 64);
            }
            if (lane == 0) {
                ws[(size_t)token * 4 + (side ? 2 : 0)] = w;
                ws[(size_t)token * 4 + (side ? 3 : 1)] = c;
            }
        }
    }
}

__global__ __launch_bounds__(1024) void router_finalize(
    const float* __restrict__ ws, float* __restrict__ out)
{
    __shared__ double red[16][4];
    const int t = threadIdx.x, lane = t & 63, w = t >> 6;
    double wq = 0, cq = 0, wv = 0, cv = 0;
    const float4* w4 = (const float4*)ws;     // [token] = {wq, cq, wv, cv}
    for (int i = t; i < NTOK; i += 1024) {
        float4 v = w4[i];
        wq += (double)v.x; cq += (double)v.y;
        wv += (double)v.z; cv += (double)v.w;
    }
    for (int o = 32; o; o >>= 1) {
        wq += __shfl_down(wq, o, 64);
        cq += __shfl_down(cq, o, 64);
        wv += __shfl_down(wv, o, 64);
        cv += __shfl_down(cv, o, 64);
    }
    if (lane == 0) { red[w][0] = wq; red[w][1] = cq; red[w][2] = wv; red[w][3] = cv; }
    __syncthreads();
    if (t == 0) {
        double a = 0, b = 0, c = 0, d = 0;
        for (int i = 0; i < 16; ++i) {
            a += red[i][0]; b += red[i][1]; c += red[i][2]; d += red[i][3];
        }
        out[OUT_GATES] = (float)(a / (b + 1e-8) + c / (d + 1e-8));
    }
}

extern "C" void kernel_launch(void* const* d_in, const int* in_sizes, int n_in,
                              void* d_out, int out_size, void* d_ws, size_t ws_size,
                              hipStream_t stream) {
    const float* x          = (const float*)d_in[0];
    const float* qk_neurons = (const float*)d_in[1];
    const float* v_neurons  = (const float*)d_in[2];
    const float* neuron_pos = (const float*)d_in[3];
    const float* W_pos_qk   = (const float*)d_in[4];
    const float* b_pos_qk   = (const float*)d_in[5];
    const float* W_pos_v    = (const float*)d_in[6];
    const float* b_pos_v    = (const float*)d_in[7];
    const float* W_tau      = (const float*)d_in[8];
    const float* b_tau      = (const float*)d_in[9];
    const int*   cm_qk      = (const int*)d_in[10];
    const int*   cm_v       = (const int*)d_in[11];

    float* out = (float*)d_out;
    float* ws  = (float*)d_ws;

    router_main<<<NTOK, 256, 0, stream>>>(
        x, qk_neurons, v_neurons, neuron_pos,
        W_pos_qk, b_pos_qk, W_pos_v, b_pos_v, W_tau, b_tau,
        cm_qk, cm_v, out, ws);
    router_finalize<<<1, 1024, 0, stream>>>(ws, out);
}

// Round 16
// 191.328 us; speedup vs baseline: 1.5070x; 1.0155x over previous
//
#include <hip/hip_runtime.h>
#include <math.h>

// Problem constants
#define BB 2
#define SS 2048
#define DD 256
#define NTOK (BB * SS)          // 4096
#define N_QK 8192
#define N_V  8192
#define NCPS 32
#define MPC  16
#define NC   144                // 9 * MPC candidates per side
#define K_QK 32
#define K_V  64
#define OUT_GATES (3 * NTOK * NC)   // offset of pos_loss scalar

__global__ __launch_bounds__(256) void router_main(
    const float* __restrict__ x,
    const float* __restrict__ qk_neurons,
    const float* __restrict__ v_neurons,
    const float* __restrict__ neuron_pos,
    const float* __restrict__ W_pos_qk, const float* __restrict__ b_pos_qk,
    const float* __restrict__ W_pos_v,  const float* __restrict__ b_pos_v,
    const float* __restrict__ W_tau,    const float* __restrict__ b_tau,
    const int* __restrict__ cm_qk, const int* __restrict__ cm_v,
    float* __restrict__ out, float* __restrict__ ws)
{
    const int token = blockIdx.x;          // b*S + s
    const int tid   = threadIdx.x;
    const int lane  = tid & 63, wid = tid >> 6;

    __shared__ __align__(16) float  x_s[DD];
    __shared__ float  scal[8];             // [0..1] qk_pos, [2..3] v_pos, [4..6] tau
    __shared__ double partd[4][7];
    __shared__ int    ci_s[2][NC];         // raw cell_map entries (may be -1)
    __shared__ __align__(16) float sc_s[2][NC];  // scores (with -1e9 fill)
    __shared__ float  d_s[2][NC];          // squared pos distance
    __shared__ __align__(16) float eg3[3][NC];   // exp_gate per gate
    __shared__ float  tc2[2][NC];          // rank-threshold candidates (scores)

    // ---- Phase A: load x row, compute 7 small dots in double (exactness feeds
    //      cell coords + tau -> all discrete decisions; cost is negligible) ----
    float xv = x[(size_t)token * DD + tid];
    x_s[tid] = xv;
    float2 wqk = ((const float2*)W_pos_qk)[tid];
    float2 wv2 = ((const float2*)W_pos_v)[tid];
    double p[7];
    p[0] = (double)xv * (double)wqk.x;
    p[1] = (double)xv * (double)wqk.y;
    p[2] = (double)xv * (double)wv2.x;
    p[3] = (double)xv * (double)wv2.y;
    p[4] = (double)xv * (double)W_tau[tid * 3 + 0];
    p[5] = (double)xv * (double)W_tau[tid * 3 + 1];
    p[6] = (double)xv * (double)W_tau[tid * 3 + 2];
    #pragma unroll
    for (int j = 0; j < 7; ++j) {
        double v = p[j];
        for (int o = 32; o; o >>= 1) v += __shfl_down(v, o, 64);
        p[j] = v;
    }
    if (lane == 0) {
        #pragma unroll
        for (int j = 0; j < 7; ++j) partd[wid][j] = p[j];
    }
    __syncthreads();
    if (tid < 7) {
        double v = partd[0][tid] + partd[1][tid] + partd[2][tid] + partd[3][tid];
        float bias = (tid < 2) ? b_pos_qk[tid]
                   : (tid < 4) ? b_pos_v[tid - 2]
                               : b_tau[tid - 4];
        scal[tid] = (float)v + bias;       // f32 dot result + f32 bias (matches ref order)
    }
    __syncthreads();

    // ---- Phase B: candidate lookup + position distances ----
    for (int c = tid; c < 2 * NC; c += 256) {
        int side = (c >= NC);
        int n    = side ? c - NC : c;
        float px = scal[side * 2 + 0], py = scal[side * 2 + 1];
        int cx = (int)(((px + 4.0f) / 8.0f) * 32.0f);
        int cy = (int)(((py + 4.0f) / 8.0f) * 32.0f);
        cx = min(max(cx, 0), NCPS - 1);
        cy = min(max(cy, 0), NCPS - 1);
        int o = n / MPC, slot = n % MPC;
        int nx = min(max(cx + (o / 3 - 1), 0), NCPS - 1);
        int ny = min(max(cy + (o % 3 - 1), 0), NCPS - 1);
        int idx = nx * NCPS + ny;
        int cand = (side ? cm_v : cm_qk)[idx * MPC + slot];
        ci_s[side][n] = cand;
        const float* npos = neuron_pos + (side ? (size_t)N_QK * 2 : 0);
        int cidx = max(cand, 0);
        float dx = px - npos[cidx * 2 + 0];
        float dy = py - npos[cidx * 2 + 1];
        d_s[side][n] = dx * dx + dy * dy;
    }
    __syncthreads();

    // ---- Phase C: 288 dots; quad-of-lanes per row, TWO rows per iteration (ILP),
    //      f32 accumulation in 4 independent chains (error ~2e-7 << kth-gap ~1e-2) ----
    {
        const int quad = tid >> 2, ql = tid & 3;   // quad 0..63
        const float4* x4 = (const float4*)x_s;
        #pragma unroll
        for (int j = 0; j < 4; j += 2) {
            const int c0 = quad + 64 * j, c1 = quad + 64 * (j + 1);
            const int side0 = (c0 >= NC), n0 = c0 - side0 * NC;
            const int side1 = (c1 >= NC), n1 = c1 - side1 * NC;
            const int cand0 = ci_s[side0][n0];
            const int cand1 = ci_s[side1][n1];
            const float4* r0 = (const float4*)((side0 ? v_neurons : qk_neurons)
                                               + (size_t)max(cand0, 0) * DD);
            const float4* r1 = (const float4*)((side1 ? v_neurons : qk_neurons)
                                               + (size_t)max(cand1, 0) * DD);
            float a0x = 0.f, a0y = 0.f, a0z = 0.f, a0w = 0.f;
            float a1x = 0.f, a1y = 0.f, a1z = 0.f, a1w = 0.f;
            #pragma unroll
            for (int i = ql; i < 64; i += 4) {
                float4 ra = r0[i];
                float4 rb = r1[i];
                float4 xx = x4[i];
                a0x = fmaf(ra.x, xx.x, a0x);
                a0y = fmaf(ra.y, xx.y, a0y);
                a0z = fmaf(ra.z, xx.z, a0z);
                a0w = fmaf(ra.w, xx.w, a0w);
                a1x = fmaf(rb.x, xx.x, a1x);
                a1y = fmaf(rb.y, xx.y, a1y);
                a1z = fmaf(rb.z, xx.z, a1z);
                a1w = fmaf(rb.w, xx.w, a1w);
            }
            float acc0 = (a0x + a0y) + (a0z + a0w);
            float acc1 = (a1x + a1y) + (a1z + a1w);
            acc0 += __shfl_xor(acc0, 1, 64);
            acc0 += __shfl_xor(acc0, 2, 64);
            acc1 += __shfl_xor(acc1, 1, 64);
            acc1 += __shfl_xor(acc1, 2, 64);
            if (ql == 0) {
                sc_s[side0][n0] = (cand0 >= 0) ? acc0 : -1e9f;
                sc_s[side1][n1] = (cand1 >= 0) ? acc1 : -1e9f;
            }
        }
        // tail: rows 256..287 handled by quads 0..31
        if (quad < 32) {
            const int c0 = 256 + quad;             // always side 1
            const int n0 = c0 - NC;
            const int cand0 = ci_s[1][n0];
            const float4* r0 = (const float4*)(v_neurons + (size_t)max(cand0, 0) * DD);
            float ax = 0.f, ay = 0.f, az = 0.f, aw = 0.f;
            #pragma unroll
            for (int i = ql; i < 64; i += 4) {
                float4 ra = r0[i];
                float4 xx = x4[i];
                ax = fmaf(ra.x, xx.x, ax);
                ay = fmaf(ra.y, xx.y, ay);
                az = fmaf(ra.z, xx.z, az);
                aw = fmaf(ra.w, xx.w, aw);
            }
            float acc = (ax + ay) + (az + aw);
            acc += __shfl_xor(acc, 1, 64);
            acc += __shfl_xor(acc, 2, 64);
            if (ql == 0) sc_s[1][n0] = (cand0 >= 0) ? acc : -1e9f;
        }
    }
    __syncthreads();

    // ---- Phase D1: exp_gate for all 3 gates ----
    for (int idx = tid; idx < 3 * NC; idx += 256) {
        int g = (idx >= 2 * NC) ? 2 : (idx >= NC);
        int j = idx - g * NC;
        float s   = sc_s[g == 2][j];
        float raw = s - scal[4 + g];
        float gate = (raw > 0.0f) ? raw : 1e-8f * expf(raw);
        eg3[g][j] = expf(gate) - 1.0f;
    }
    // ---- Phase D2: rank candidates on SCORES (monotonic h => same k-th element) ----
    for (int idx = tid; idx < 2 * NC; idx += 256) {
        int side = (idx >= NC);
        int n    = idx - side * NC;
        float my = sc_s[side][n];
        const float4* s4 = (const float4*)&sc_s[side][0];
        int cnt = 0;
        #pragma unroll
        for (int q = 0; q < NC / 4; ++q) {
            float4 e = s4[q];
            cnt += (e.x > my) + (e.y > my) + (e.z > my) + (e.w > my);
        }
        int k = side ? K_V : K_QK;
        tc2[side][n] = (cnt < k) ? my : 3.402823466e38f;
    }
    __syncthreads();

    // ---- Phase D3: one wave per gate ----
    if (wid < 3) {
        const int g = wid, side = (g == 2);
        const bool has2 = (lane < 16);
        float t0 = tc2[side][lane], t1 = tc2[side][lane + 64];
        float t2 = has2 ? tc2[side][lane + 128] : 3.402823466e38f;
        float e0 = eg3[g][lane],   e1 = eg3[g][lane + 64];
        float e2 = has2 ? eg3[g][lane + 128] : 0.0f;
        float mn = fminf(fminf(t0, t1), t2);
        float mx = fmaxf(fmaxf(e0, e1), e2);
        #pragma unroll
        for (int o = 32; o; o >>= 1) {
            mn = fminf(mn, __shfl_xor(mn, o, 64));
            mx = fmaxf(mx, __shfl_xor(mx, o, 64));
        }
        // thr = h(s_k, tau_g): identical f32 ops as D1 => bit-identical to ref's k-th eg
        float rawk  = mn - scal[4 + g];
        float gatek = (rawk > 0.0f) ? rawk : 1e-8f * expf(rawk);
        float thr   = expf(gatek) - 1.0f;

        float k0 = (e0 >= thr) ? e0 : 0.0f;
        float k1 = (e1 >= thr) ? e1 : 0.0f;
        float k2 = (has2 && e2 >= thr) ? e2 : 0.0f;
        float sum = k0 + k1 + k2;
        #pragma unroll
        for (int o = 32; o; o >>= 1) sum += __shfl_xor(sum, o, 64);
        const float gs = sum + 1e-8f;
        const float strength = tanhf(mx);
        float o0 = k0 / gs * strength;
        float o1 = k1 / gs * strength;
        float o2 = k2 / gs * strength;
        float* og = out + ((size_t)g * NTOK + token) * NC;
        og[lane]      = o0;
        og[lane + 64] = o1;
        if (has2) og[lane + 128] = o2;

        if (g != 1) {
            float m0 = (ci_s[side][lane]       >= 0) ? 1.0f : 0.0f;
            float m1 = (ci_s[side][lane + 64]  >= 0) ? 1.0f : 0.0f;
            float m2 = (has2 && ci_s[side][lane + 128] >= 0) ? 1.0f : 0.0f;
            float w = o0 * d_s[side][lane] * m0 + o1 * d_s[side][lane + 64] * m1;
            if (has2) w += o2 * d_s[side][lane + 128] * m2;
            float c = m0 + m1 + m2;
            #pragma unroll
            for (int o = 32; o; o >>= 1) {
                w += __shfl_xor(w, o, 64);
                c += __shfl_xor(c, o, 64);
            }
            if (lane == 0) {
                ws[(size_t)token * 4 + (side ? 2 : 0)] = w;
                ws[(size_t)token * 4 + (side ? 3 : 1)] = c;
            }
        }
    }
}

__global__ __launch_bounds__(1024) void router_finalize(
    const float* __restrict__ ws, float* __restrict__ out)
{
    __shared__ double red[16][4];
    const int t = threadIdx.x, lane = t & 63, w = t >> 6;
    double wq = 0, cq = 0, wv = 0, cv = 0;
    const float4* w4 = (const float4*)ws;     // [token] = {wq, cq, wv, cv}
    for (int i = t; i < NTOK; i += 1024) {
        float4 v = w4[i];
        wq += (double)v.x; cq += (double)v.y;
        wv += (double)v.z; cv += (double)v.w;
    }
    for (int o = 32; o; o >>= 1) {
        wq += __shfl_down(wq, o, 64);
        cq += __shfl_down(cq, o, 64);
        wv += __shfl_down(wv, o, 64);
        cv += __shfl_down(cv, o, 64);
    }
    if (lane == 0) { red[w][0] = wq; red[w][1] = cq; red[w][2] = wv; red[w][3] = cv; }
    __syncthreads();
    if (t == 0) {
        double a = 0, b = 0, c = 0, d = 0;
        for (int i = 0; i < 16; ++i) {
            a += red[i][0]; b += red[i][1]; c += red[i][2]; d += red[i][3];
        }
        out[OUT_GATES] = (float)(a / (b + 1e-8) + c / (d + 1e-8));
    }
}

extern "C" void kernel_launch(void* const* d_in, const int* in_sizes, int n_in,
                              void* d_out, int out_size, void* d_ws, size_t ws_size,
                              hipStream_t stream) {
    const float* x          = (const float*)d_in[0];
    const float* qk_neurons = (const float*)d_in[1];
    const float* v_neurons  = (const float*)d_in[2];
    const float* neuron_pos = (const float*)d_in[3];
    const float* W_pos_qk   = (const float*)d_in[4];
    const float* b_pos_qk   = (const float*)d_in[5];
    const float* W_pos_v    = (const float*)d_in[6];
    const float* b_pos_v    = (const float*)d_in[7];
    const float* W_tau      = (const float*)d_in[8];
    const float* b_tau      = (const float*)d_in[9];
    const int*   cm_qk      = (const int*)d_in[10];
    const int*   cm_v       = (const int*)d_in[11];

    float* out = (float*)d_out;
    float* ws  = (float*)d_ws;

    router_main<<<NTOK, 256, 0, stream>>>(
        x, qk_neurons, v_neurons, neuron_pos,
        W_pos_qk, b_pos_qk, W_pos_v, b_pos_v, W_tau, b_tau,
        cm_qk, cm_v, out, ws);
    router_finalize<<<1, 1024, 0, stream>>>(ws, out);
}